// Round 6
// baseline (165.421 us; speedup 1.0000x reference)
//
#include <hip/hip_runtime.h>
#include <hip/hip_bf16.h>

#define BS   16
#define NA   8400
#define NMB  100
#define NC   80
#define TOPK 13
#define EPS  1e-9f

typedef float f32x4 __attribute__((ext_vector_type(4)));

// output layout (floats): labels [BS,NA] | bboxes [BS,NA,4] | scores [BS,NA,NC] | fg [BS,NA]
#define OUT_LABELS 0
#define OUT_BBOX   (BS * NA)
#define OUT_SCORES (BS * NA * 5)
#define OUT_FG     (BS * NA * 5 + BS * NA * NC)

// ws (u32 units): posalign[1600] | posover[1600] | ids[1600*13] | alignbuf f32[BS*NA] | idxbuf i32[BS*NA]
#define PA_OFF   0
#define PO_OFF   (BS * NMB)
#define IDS_OFF  (2 * BS * NMB)
#define AB_OFF   (2 * BS * NMB + BS * NMB * TOPK)
#define IDX_OFF  (AB_OFF + BS * NA)

__device__ __forceinline__ float iou_xyxy(float4 g, float4 p) {
    float lx = fmaxf(g.x, p.x), ly = fmaxf(g.y, p.y);
    float rx = fminf(g.z, p.z), ry = fminf(g.w, p.w);
    float w = fmaxf(rx - lx, 0.f), h = fmaxf(ry - ly, 0.f);
    float inter = w * h;
    float ag = (g.z - g.x) * (g.w - g.y);
    float ap = (p.z - p.x) * (p.w - p.y);
    return inter / (ag + ap - inter + EPS);
}

// fast unsigned divide for small c (<4096), w (<128): rcp + correction
__device__ __forceinline__ void fdivmod(int c, int w, float rw, int& q, int& r) {
    q = (int)((float)c * rw);
    r = c - q * w;
    if (r < 0) { q--; r += w; }
    else if (r >= w) { q++; r -= w; }
}

// One WAVE per (b,m). Candidates = in-box anchors (3 padded rectangular grid
// ranges, exact ins filter) + anchors {0..12} (the only possible zero-value
// tie-break picks), deduped. Top-13 via 13 rounds of wave argmax on packed
// (value<<32 | ~idx) keys -> exact jax.lax.top_k order (value desc, idx asc).
// Winners go to a compact ids list (sentinel ~0u when !is_in_gts or masked GT);
// also zeroes this GT's posalign/posover (no separate init kernel).
__global__ __launch_bounds__(64) void k_topk(
        const float* __restrict__ scores, const float* __restrict__ pboxes,
        const float* __restrict__ gboxes, const float* __restrict__ maskgt,
        const int* __restrict__ glabels,
        unsigned int* __restrict__ ids,
        unsigned int* __restrict__ posalign, unsigned int* __restrict__ posover) {
    int bid = blockIdx.x;
    int bm = (bid & 7) * 200 + (bid >> 3);     // 8 XCDs x 200: 2 batches per XCD
    int lane = threadIdx.x;
    if (lane == 0) posalign[bm] = 0u;          // replaces k_init
    if (lane == 1) posover[bm] = 0u;
    if (maskgt[bm] <= 0.f) {
        if (lane < TOPK) ids[bm * TOPK + lane] = 0xFFFFFFFFu;
        return;
    }
    int b = bm / NMB;
    float4 g = ((const float4*)gboxes)[bm];
    int lbl = glabels[bm];
    const float* srow = scores + (size_t)b * NA * NC + lbl;
    const float4* pb = (const float4*)pboxes + (size_t)b * NA;

    // padded index ranges per level; ins test below is the exact filter.
    int x0, y0, w0, h0, x1r, y1r, w1, h1, x2r, y2r, w2, h2;
    {
        float s = 8.f; int n = 80;
        x0 = (int)floorf((g.x + EPS) / s - 0.5f); if (x0 < 0) x0 = 0;
        int xh = (int)ceilf((g.z - EPS) / s - 0.5f); if (xh > n - 1) xh = n - 1;
        y0 = (int)floorf((g.y + EPS) / s - 0.5f); if (y0 < 0) y0 = 0;
        int yh = (int)ceilf((g.w - EPS) / s - 0.5f); if (yh > n - 1) yh = n - 1;
        w0 = xh - x0 + 1; if (w0 < 0) w0 = 0;
        h0 = yh - y0 + 1; if (h0 < 0) h0 = 0;
    }
    {
        float s = 16.f; int n = 40;
        x1r = (int)floorf((g.x + EPS) / s - 0.5f); if (x1r < 0) x1r = 0;
        int xh = (int)ceilf((g.z - EPS) / s - 0.5f); if (xh > n - 1) xh = n - 1;
        y1r = (int)floorf((g.y + EPS) / s - 0.5f); if (y1r < 0) y1r = 0;
        int yh = (int)ceilf((g.w - EPS) / s - 0.5f); if (yh > n - 1) yh = n - 1;
        w1 = xh - x1r + 1; if (w1 < 0) w1 = 0;
        h1 = yh - y1r + 1; if (h1 < 0) h1 = 0;
    }
    {
        float s = 32.f; int n = 20;
        x2r = (int)floorf((g.x + EPS) / s - 0.5f); if (x2r < 0) x2r = 0;
        int xh = (int)ceilf((g.z - EPS) / s - 0.5f); if (xh > n - 1) xh = n - 1;
        y2r = (int)floorf((g.y + EPS) / s - 0.5f); if (y2r < 0) y2r = 0;
        int yh = (int)ceilf((g.w - EPS) / s - 0.5f); if (yh > n - 1) yh = n - 1;
        w2 = xh - x2r + 1; if (w2 < 0) w2 = 0;
        h2 = yh - y2r + 1; if (h2 < 0) h2 = 0;
    }
    int n0 = w0 * h0, n01 = n0 + w1 * h1, n012 = n01 + w2 * h2;
    int N = n012 + TOPK;                       // <= ~570 + 13 <= 640 = 64*10
    float rw0 = __builtin_amdgcn_rcpf((float)w0);
    float rw1 = __builtin_amdgcn_rcpf((float)w1);
    float rw2 = __builtin_amdgcn_rcpf((float)w2);

    unsigned long long key[10];
    unsigned int insmask = 0;
    #pragma unroll
    for (int j = 0; j < 10; ++j) {
        key[j] = 0ull;
        int c = lane + j * 64;
        if (c < N) {
            int a; float ax, ay; bool dup = false;
            if (c < n0) {
                int iy, ix; fdivmod(c, w0, rw0, iy, ix);
                iy += y0; ix += x0;
                a = iy * 80 + ix; ax = (ix + 0.5f) * 8.f; ay = (iy + 0.5f) * 8.f;
            } else if (c < n01) {
                int iy, ix; fdivmod(c - n0, w1, rw1, iy, ix);
                iy += y1r; ix += x1r;
                a = 6400 + iy * 40 + ix; ax = (ix + 0.5f) * 16.f; ay = (iy + 0.5f) * 16.f;
            } else if (c < n012) {
                int iy, ix; fdivmod(c - n01, w2, rw2, iy, ix);
                iy += y2r; ix += x2r;
                a = 8000 + iy * 20 + ix; ax = (ix + 0.5f) * 32.f; ay = (iy + 0.5f) * 32.f;
            } else {
                a = c - n012;                  // supplement: L0 row 0, ix=a
                ax = (a + 0.5f) * 8.f; ay = 4.0f;
                dup = (h0 > 0) && (y0 == 0) && (w0 > 0) && (x0 <= a) && (a <= x0 + w0 - 1);
            }
            if (!dup) {
                float4 p = pb[a];
                float sc = srow[(size_t)a * NC];
                float ov = iou_xyxy(g, p);
                bool ins = fminf(fminf(ax - g.x, ay - g.y),
                                 fminf(g.z - ax, g.w - ay)) > EPS;
                float o2 = ov * ov;
                float val = ins ? sc * o2 * o2 * o2 : 0.f;
                key[j] = ((unsigned long long)__float_as_uint(val) << 32)
                       | (unsigned)(0xFFFFFFFFu - (unsigned)a);
                if (ins) insmask |= (1u << j);
            }
        }
    }

    for (int r = 0; r < TOPK; ++r) {
        unsigned long long best = 0ull;
        #pragma unroll
        for (int j = 0; j < 10; ++j) if (key[j] > best) best = key[j];
        #pragma unroll
        for (int off = 32; off >= 1; off >>= 1) {
            unsigned long long o = __shfl_xor(best, off, 64);
            if (o > best) best = o;
        }
        #pragma unroll
        for (int j = 0; j < 10; ++j) {
            if (key[j] == best) {              // unique owner (>=13 nonzero keys)
                key[j] = 0ull;
                int a = (int)(0xFFFFFFFFu - (unsigned)best);
                ids[bm * TOPK + r] = ((insmask >> j) & 1u) ? (unsigned)a
                                                           : 0xFFFFFFFFu;
            }
        }
    }
}

// One thread per (b,a); per-batch blocks (33 per batch). Derives (cnt, min-m)
// from the 1300-entry ids list in LDS with a strictly-inside prefilter
// (identical float expr to k_topk's ins -> only real winners can match).
// Collision resolution, labels/bboxes/fg outputs, per-GT maxima atomics.
__global__ __launch_bounds__(256) void k_resolve(
        const float* __restrict__ scores, const float* __restrict__ pboxes,
        const float* __restrict__ gboxes, const int* __restrict__ glabels,
        const unsigned int* __restrict__ ids,
        unsigned int* __restrict__ posalign, unsigned int* __restrict__ posover,
        float* __restrict__ alignbuf, int* __restrict__ idxbuf,
        float* __restrict__ out) {
    __shared__ unsigned int s_ids[NMB * TOPK];
    __shared__ float4 s_g[NMB];
    __shared__ int s_lbl[NMB];
    int blk = blockIdx.x;
    int b = blk / 33;
    int a = (blk - b * 33) * 256 + threadIdx.x;
    for (int i = threadIdx.x; i < NMB * TOPK; i += 256)
        s_ids[i] = ids[b * NMB * TOPK + i];
    for (int i = threadIdx.x; i < NMB; i += 256) {
        s_g[i] = ((const float4*)gboxes)[b * NMB + i];
        s_lbl[i] = glabels[b * NMB + i];
    }
    __syncthreads();
    if (a >= NA) return;
    int t = b * NA + a;

    // anchor center from index (exact same values as the reference grid)
    float ax, ay;
    if (a < 6400)      { int iy = a / 80,  ix = a - iy * 80;
                         ax = (ix + 0.5f) * 8.f;  ay = (iy + 0.5f) * 8.f; }
    else if (a < 8000) { int r = a - 6400; int iy = r / 40, ix = r - iy * 40;
                         ax = (ix + 0.5f) * 16.f; ay = (iy + 0.5f) * 16.f; }
    else               { int r = a - 8000; int iy = r / 20, ix = r - iy * 20;
                         ax = (ix + 0.5f) * 32.f; ay = (iy + 0.5f) * 32.f; }

    int cnt = 0, first = 0;
    for (int m = 0; m < NMB; ++m) {
        float4 gg = s_g[m];
        if (fminf(fminf(ax - gg.x, ay - gg.y),
                  fminf(gg.z - ax, gg.w - ay)) > EPS) {
            #pragma unroll
            for (int r = 0; r < TOPK; ++r) {
                if (s_ids[m * TOPK + r] == (unsigned)a) {
                    if (cnt == 0) first = m;
                    ++cnt;
                    break;
                }
            }
        }
    }

    float4 p = ((const float4*)pboxes)[t];
    int idx = 0, fg = 0;
    if (cnt > 1) {
        // multi-GT anchor -> argmax_m IoU over ALL m (first occurrence on ties)
        float best = -1.f; int bmx = 0;
        for (int m = 0; m < NMB; ++m) {
            float ov = iou_xyxy(s_g[m], p);
            if (ov > best) { best = ov; bmx = m; }
        }
        idx = bmx; fg = 1;
    } else if (cnt == 1) { idx = first; fg = 1; }

    int lbl = s_lbl[idx];
    if (lbl < 0) lbl = 0;
    float4 gb = s_g[idx];
    float al = 0.f;
    if (fg) {
        float ov = iou_xyxy(gb, p);
        float sc = scores[(size_t)t * NC + lbl];
        float o2 = ov * ov;
        al = sc * o2 * o2 * o2;                // UNMASKED align (matches ref)
        atomicMax(&posalign[b * NMB + idx], __float_as_uint(al));
        atomicMax(&posover[b * NMB + idx], __float_as_uint(ov));
    }
    alignbuf[t] = al;
    idxbuf[t] = fg ? idx : -1;
    __builtin_nontemporal_store((float)lbl, out + OUT_LABELS + t);
    f32x4 gbv = { gb.x, gb.y, gb.z, gb.w };
    __builtin_nontemporal_store(gbv, (f32x4*)(out + OUT_BBOX) + t);
    __builtin_nontemporal_store(fg ? 1.f : 0.f, out + OUT_FG + t);
}

// One thread per (b,a): after resolution each anchor has <=1 GT, so
// norm = align*pos_over/(pos_align+eps) at the single assigned GT.
// Streams the full 80-class row with nontemporal stores.
__global__ __launch_bounds__(256) void k_score(
        const float* __restrict__ alignbuf, const int* __restrict__ idxbuf,
        const int* __restrict__ glabels,
        const unsigned int* __restrict__ posalign,
        const unsigned int* __restrict__ posover,
        float* __restrict__ out) {
    int t = blockIdx.x * 256 + threadIdx.x;
    if (t >= BS * NA) return;
    int b = t / NA;
    int idx = idxbuf[t];
    float norm = 0.f; int lbl = -1;
    if (idx >= 0) {
        float pa = __uint_as_float(posalign[b * NMB + idx]);
        float po = __uint_as_float(posover[b * NMB + idx]);
        norm = alignbuf[t] * po / (pa + EPS);
        lbl = glabels[b * NMB + idx];
        if (lbl < 0) lbl = 0;
    }
    f32x4* dst = (f32x4*)(out + OUT_SCORES + (size_t)t * NC);
    #pragma unroll
    for (int q = 0; q < NC / 4; ++q) {
        int c0 = q * 4;
        f32x4 w;
        w.x = (c0     == lbl) ? norm : 0.f;
        w.y = (c0 + 1 == lbl) ? norm : 0.f;
        w.z = (c0 + 2 == lbl) ? norm : 0.f;
        w.w = (c0 + 3 == lbl) ? norm : 0.f;
        __builtin_nontemporal_store(w, dst + q);
    }
}

extern "C" void kernel_launch(void* const* d_in, const int* in_sizes, int n_in,
                              void* d_out, int out_size, void* d_ws, size_t ws_size,
                              hipStream_t stream) {
    const float* scores  = (const float*)d_in[0];   // [BS,NA,NC]
    const float* pboxes  = (const float*)d_in[1];   // [BS,NA,4]
    const float* gboxes  = (const float*)d_in[3];   // [BS,NMB,4]
    const float* maskgt  = (const float*)d_in[4];   // [BS,NMB,1]
    const int*   glabels = (const int*)d_in[5];     // [BS,NMB,1]
    float* out = (float*)d_out;

    unsigned int* ws = (unsigned int*)d_ws;
    unsigned int* posalign = ws + PA_OFF;
    unsigned int* posover  = ws + PO_OFF;
    unsigned int* idsbuf   = ws + IDS_OFF;
    float* alignbuf        = (float*)(ws + AB_OFF);
    int*   idxbuf          = (int*)(ws + IDX_OFF);

    k_topk<<<BS * NMB, 64, 0, stream>>>(scores, pboxes, gboxes, maskgt,
                                        glabels, idsbuf, posalign, posover);
    k_resolve<<<BS * 33, 256, 0, stream>>>(
        scores, pboxes, gboxes, glabels, idsbuf,
        posalign, posover, alignbuf, idxbuf, out);
    int nthr = BS * NA;
    k_score<<<(nthr + 255) / 256, 256, 0, stream>>>(
        alignbuf, idxbuf, glabels, posalign, posover, out);
}

// Round 7
// 79.520 us; speedup vs baseline: 2.0802x; 2.0802x over previous
//
#include <hip/hip_runtime.h>
#include <hip/hip_bf16.h>

#define BS   16
#define NA   8400
#define NMB  100
#define NC   80
#define TOPK 13
#define EPS  1e-9f

typedef float f32x4 __attribute__((ext_vector_type(4)));

// output layout (floats): labels [BS,NA] | bboxes [BS,NA,4] | scores [BS,NA,NC] | fg [BS,NA]
#define OUT_LABELS 0
#define OUT_BBOX   (BS * NA)
#define OUT_SCORES (BS * NA * 5)
#define OUT_FG     (BS * NA * 5 + BS * NA * NC)

// ws (u32 units): posalign[1600] | posover[1600] | ids[1600*13] | alignbuf f32[BS*NA] | idxbuf i32[BS*NA]
#define PA_OFF   0
#define PO_OFF   (BS * NMB)
#define IDS_OFF  (2 * BS * NMB)
#define AB_OFF   (2 * BS * NMB + BS * NMB * TOPK)
#define IDX_OFF  (AB_OFF + BS * NA)

__device__ __forceinline__ float iou_xyxy(float4 g, float4 p) {
    float lx = fmaxf(g.x, p.x), ly = fmaxf(g.y, p.y);
    float rx = fminf(g.z, p.z), ry = fminf(g.w, p.w);
    float w = fmaxf(rx - lx, 0.f), h = fmaxf(ry - ly, 0.f);
    float inter = w * h;
    float ag = (g.z - g.x) * (g.w - g.y);
    float ap = (p.z - p.x) * (p.w - p.y);
    return inter / (ag + ap - inter + EPS);
}

// fast unsigned divide for small c (<4096), w (<128): rcp + correction
__device__ __forceinline__ void fdivmod(int c, int w, float rw, int& q, int& r) {
    q = (int)((float)c * rw);
    r = c - q * w;
    if (r < 0) { q--; r += w; }
    else if (r >= w) { q++; r -= w; }
}

// One WAVE per (b,m). Candidates = in-box anchors (3 padded rectangular grid
// ranges, exact ins filter) + anchors {0..12} (the only possible zero-value
// tie-break picks), deduped. Top-13 via 13 rounds of wave argmax on packed
// (value<<32 | ~idx) keys -> exact jax.lax.top_k order (value desc, idx asc).
// Winners go to a compact ids list (sentinel ~0u when !is_in_gts or masked GT);
// also zeroes this GT's posalign/posover (no separate init kernel).
__global__ __launch_bounds__(64) void k_topk(
        const float* __restrict__ scores, const float* __restrict__ pboxes,
        const float* __restrict__ gboxes, const float* __restrict__ maskgt,
        const int* __restrict__ glabels,
        unsigned int* __restrict__ ids,
        unsigned int* __restrict__ posalign, unsigned int* __restrict__ posover) {
    int bid = blockIdx.x;
    int bm = (bid & 7) * 200 + (bid >> 3);     // 8 XCDs x 200: 2 batches per XCD
    int lane = threadIdx.x;
    if (lane == 0) posalign[bm] = 0u;          // replaces k_init
    if (lane == 1) posover[bm] = 0u;
    if (maskgt[bm] <= 0.f) {
        if (lane < TOPK) ids[bm * TOPK + lane] = 0xFFFFFFFFu;
        return;
    }
    int b = bm / NMB;
    float4 g = ((const float4*)gboxes)[bm];
    int lbl = glabels[bm];
    const float* srow = scores + (size_t)b * NA * NC + lbl;
    const float4* pb = (const float4*)pboxes + (size_t)b * NA;

    // padded index ranges per level; ins test below is the exact filter.
    int x0, y0, w0, h0, x1r, y1r, w1, h1, x2r, y2r, w2, h2;
    {
        float s = 8.f; int n = 80;
        x0 = (int)floorf((g.x + EPS) / s - 0.5f); if (x0 < 0) x0 = 0;
        int xh = (int)ceilf((g.z - EPS) / s - 0.5f); if (xh > n - 1) xh = n - 1;
        y0 = (int)floorf((g.y + EPS) / s - 0.5f); if (y0 < 0) y0 = 0;
        int yh = (int)ceilf((g.w - EPS) / s - 0.5f); if (yh > n - 1) yh = n - 1;
        w0 = xh - x0 + 1; if (w0 < 0) w0 = 0;
        h0 = yh - y0 + 1; if (h0 < 0) h0 = 0;
    }
    {
        float s = 16.f; int n = 40;
        x1r = (int)floorf((g.x + EPS) / s - 0.5f); if (x1r < 0) x1r = 0;
        int xh = (int)ceilf((g.z - EPS) / s - 0.5f); if (xh > n - 1) xh = n - 1;
        y1r = (int)floorf((g.y + EPS) / s - 0.5f); if (y1r < 0) y1r = 0;
        int yh = (int)ceilf((g.w - EPS) / s - 0.5f); if (yh > n - 1) yh = n - 1;
        w1 = xh - x1r + 1; if (w1 < 0) w1 = 0;
        h1 = yh - y1r + 1; if (h1 < 0) h1 = 0;
    }
    {
        float s = 32.f; int n = 20;
        x2r = (int)floorf((g.x + EPS) / s - 0.5f); if (x2r < 0) x2r = 0;
        int xh = (int)ceilf((g.z - EPS) / s - 0.5f); if (xh > n - 1) xh = n - 1;
        y2r = (int)floorf((g.y + EPS) / s - 0.5f); if (y2r < 0) y2r = 0;
        int yh = (int)ceilf((g.w - EPS) / s - 0.5f); if (yh > n - 1) yh = n - 1;
        w2 = xh - x2r + 1; if (w2 < 0) w2 = 0;
        h2 = yh - y2r + 1; if (h2 < 0) h2 = 0;
    }
    int n0 = w0 * h0, n01 = n0 + w1 * h1, n012 = n01 + w2 * h2;
    int N = n012 + TOPK;                       // <= ~570 + 13 <= 640 = 64*10
    float rw0 = __builtin_amdgcn_rcpf((float)w0);
    float rw1 = __builtin_amdgcn_rcpf((float)w1);
    float rw2 = __builtin_amdgcn_rcpf((float)w2);

    unsigned long long key[10];
    unsigned int insmask = 0;
    #pragma unroll
    for (int j = 0; j < 10; ++j) {
        key[j] = 0ull;
        int c = lane + j * 64;
        if (c < N) {
            int a; float ax, ay; bool dup = false;
            if (c < n0) {
                int iy, ix; fdivmod(c, w0, rw0, iy, ix);
                iy += y0; ix += x0;
                a = iy * 80 + ix; ax = (ix + 0.5f) * 8.f; ay = (iy + 0.5f) * 8.f;
            } else if (c < n01) {
                int iy, ix; fdivmod(c - n0, w1, rw1, iy, ix);
                iy += y1r; ix += x1r;
                a = 6400 + iy * 40 + ix; ax = (ix + 0.5f) * 16.f; ay = (iy + 0.5f) * 16.f;
            } else if (c < n012) {
                int iy, ix; fdivmod(c - n01, w2, rw2, iy, ix);
                iy += y2r; ix += x2r;
                a = 8000 + iy * 20 + ix; ax = (ix + 0.5f) * 32.f; ay = (iy + 0.5f) * 32.f;
            } else {
                a = c - n012;                  // supplement: L0 row 0, ix=a
                ax = (a + 0.5f) * 8.f; ay = 4.0f;
                dup = (h0 > 0) && (y0 == 0) && (w0 > 0) && (x0 <= a) && (a <= x0 + w0 - 1);
            }
            if (!dup) {
                float4 p = pb[a];
                float sc = srow[(size_t)a * NC];
                float ov = iou_xyxy(g, p);
                bool ins = fminf(fminf(ax - g.x, ay - g.y),
                                 fminf(g.z - ax, g.w - ay)) > EPS;
                float o2 = ov * ov;
                float val = ins ? sc * o2 * o2 * o2 : 0.f;
                key[j] = ((unsigned long long)__float_as_uint(val) << 32)
                       | (unsigned)(0xFFFFFFFFu - (unsigned)a);
                if (ins) insmask |= (1u << j);
            }
        }
    }

    for (int r = 0; r < TOPK; ++r) {
        unsigned long long best = 0ull;
        #pragma unroll
        for (int j = 0; j < 10; ++j) if (key[j] > best) best = key[j];
        #pragma unroll
        for (int off = 32; off >= 1; off >>= 1) {
            unsigned long long o = __shfl_xor(best, off, 64);
            if (o > best) best = o;
        }
        #pragma unroll
        for (int j = 0; j < 10; ++j) {
            if (key[j] == best) {              // unique owner (>=13 nonzero keys)
                key[j] = 0ull;
                int a = (int)(0xFFFFFFFFu - (unsigned)best);
                ids[bm * TOPK + r] = ((insmask >> j) & 1u) ? (unsigned)a
                                                           : 0xFFFFFFFFu;
            }
        }
    }
}

// One thread per (b,a); per-batch blocks (33 per batch). Derives (cnt, min-m)
// from the 1300-entry ids list in LDS with a strictly-inside prefilter
// (identical float expr to k_topk's ins -> only real winners can match).
// Collision resolution, labels/bboxes/fg outputs, per-GT maxima atomics.
__global__ __launch_bounds__(256) void k_resolve(
        const float* __restrict__ scores, const float* __restrict__ pboxes,
        const float* __restrict__ gboxes, const int* __restrict__ glabels,
        const unsigned int* __restrict__ ids,
        unsigned int* __restrict__ posalign, unsigned int* __restrict__ posover,
        float* __restrict__ alignbuf, int* __restrict__ idxbuf,
        float* __restrict__ out) {
    __shared__ unsigned int s_ids[NMB * TOPK];
    __shared__ float4 s_g[NMB];
    __shared__ int s_lbl[NMB];
    int blk = blockIdx.x;
    int b = blk / 33;
    int a = (blk - b * 33) * 256 + threadIdx.x;
    for (int i = threadIdx.x; i < NMB * TOPK; i += 256)
        s_ids[i] = ids[b * NMB * TOPK + i];
    for (int i = threadIdx.x; i < NMB; i += 256) {
        s_g[i] = ((const float4*)gboxes)[b * NMB + i];
        s_lbl[i] = glabels[b * NMB + i];
    }
    __syncthreads();
    if (a >= NA) return;
    int t = b * NA + a;

    // anchor center from index (exact same values as the reference grid)
    float ax, ay;
    if (a < 6400)      { int iy = a / 80,  ix = a - iy * 80;
                         ax = (ix + 0.5f) * 8.f;  ay = (iy + 0.5f) * 8.f; }
    else if (a < 8000) { int r = a - 6400; int iy = r / 40, ix = r - iy * 40;
                         ax = (ix + 0.5f) * 16.f; ay = (iy + 0.5f) * 16.f; }
    else               { int r = a - 8000; int iy = r / 20, ix = r - iy * 20;
                         ax = (ix + 0.5f) * 32.f; ay = (iy + 0.5f) * 32.f; }

    int cnt = 0, first = 0;
    for (int m = 0; m < NMB; ++m) {
        float4 gg = s_g[m];
        if (fminf(fminf(ax - gg.x, ay - gg.y),
                  fminf(gg.z - ax, gg.w - ay)) > EPS) {
            #pragma unroll
            for (int r = 0; r < TOPK; ++r) {
                if (s_ids[m * TOPK + r] == (unsigned)a) {
                    if (cnt == 0) first = m;
                    ++cnt;
                    break;
                }
            }
        }
    }

    float4 p = ((const float4*)pboxes)[t];
    int idx = 0, fg = 0;
    if (cnt > 1) {
        // multi-GT anchor -> argmax_m IoU over ALL m (first occurrence on ties)
        float best = -1.f; int bmx = 0;
        for (int m = 0; m < NMB; ++m) {
            float ov = iou_xyxy(s_g[m], p);
            if (ov > best) { best = ov; bmx = m; }
        }
        idx = bmx; fg = 1;
    } else if (cnt == 1) { idx = first; fg = 1; }

    int lbl = s_lbl[idx];
    if (lbl < 0) lbl = 0;
    float4 gb = s_g[idx];
    float al = 0.f;
    if (fg) {
        float ov = iou_xyxy(gb, p);
        float sc = scores[(size_t)t * NC + lbl];
        float o2 = ov * ov;
        al = sc * o2 * o2 * o2;                // UNMASKED align (matches ref)
        atomicMax(&posalign[b * NMB + idx], __float_as_uint(al));
        atomicMax(&posover[b * NMB + idx], __float_as_uint(ov));
    }
    alignbuf[t] = al;
    idxbuf[t] = fg ? idx : -1;
    out[OUT_LABELS + t] = (float)lbl;
    ((float4*)(out + OUT_BBOX))[t] = gb;
    out[OUT_FG + t] = fg ? 1.f : 0.f;
}

// One thread per 16-byte chunk of the score output (20 chunks per anchor).
// Fully coalesced plain float4 stores through L2 (write-combining).
// norm = align*pos_over/(pos_align+eps) at the single assigned GT.
__global__ __launch_bounds__(256) void k_score(
        const float* __restrict__ alignbuf, const int* __restrict__ idxbuf,
        const int* __restrict__ glabels,
        const unsigned int* __restrict__ posalign,
        const unsigned int* __restrict__ posover,
        float* __restrict__ out) {
    int i = blockIdx.x * 256 + threadIdx.x;
    if (i >= BS * NA * (NC / 4)) return;
    int t = i / (NC / 4), q = i - t * (NC / 4);   // anchor, chunk
    int b = t / NA;
    int idx = idxbuf[t];
    float norm = 0.f; int lbl = -1;
    if (idx >= 0) {
        float pa = __uint_as_float(posalign[b * NMB + idx]);
        float po = __uint_as_float(posover[b * NMB + idx]);
        norm = alignbuf[t] * po / (pa + EPS);
        lbl = glabels[b * NMB + idx];
        if (lbl < 0) lbl = 0;
    }
    int c0 = q * 4;
    f32x4 w;
    w.x = (c0     == lbl) ? norm : 0.f;
    w.y = (c0 + 1 == lbl) ? norm : 0.f;
    w.z = (c0 + 2 == lbl) ? norm : 0.f;
    w.w = (c0 + 3 == lbl) ? norm : 0.f;
    ((f32x4*)(out + OUT_SCORES))[i] = w;
}

extern "C" void kernel_launch(void* const* d_in, const int* in_sizes, int n_in,
                              void* d_out, int out_size, void* d_ws, size_t ws_size,
                              hipStream_t stream) {
    const float* scores  = (const float*)d_in[0];   // [BS,NA,NC]
    const float* pboxes  = (const float*)d_in[1];   // [BS,NA,4]
    const float* gboxes  = (const float*)d_in[3];   // [BS,NMB,4]
    const float* maskgt  = (const float*)d_in[4];   // [BS,NMB,1]
    const int*   glabels = (const int*)d_in[5];     // [BS,NMB,1]
    float* out = (float*)d_out;

    unsigned int* ws = (unsigned int*)d_ws;
    unsigned int* posalign = ws + PA_OFF;
    unsigned int* posover  = ws + PO_OFF;
    unsigned int* idsbuf   = ws + IDS_OFF;
    float* alignbuf        = (float*)(ws + AB_OFF);
    int*   idxbuf          = (int*)(ws + IDX_OFF);

    k_topk<<<BS * NMB, 64, 0, stream>>>(scores, pboxes, gboxes, maskgt,
                                        glabels, idsbuf, posalign, posover);
    k_resolve<<<BS * 33, 256, 0, stream>>>(
        scores, pboxes, gboxes, glabels, idsbuf,
        posalign, posover, alignbuf, idxbuf, out);
    int nchunk = BS * NA * (NC / 4);
    k_score<<<(nchunk + 255) / 256, 256, 0, stream>>>(
        alignbuf, idxbuf, glabels, posalign, posover, out);
}

// Round 8
// 59.937 us; speedup vs baseline: 2.7599x; 1.3267x over previous
//
#include <hip/hip_runtime.h>
#include <hip/hip_bf16.h>

#define BS   16
#define NA   8400
#define NMB  100
#define NC   80
#define TOPK 13
#define EPS  1e-9f

typedef float f32x4 __attribute__((ext_vector_type(4)));

// output layout (floats): labels [BS,NA] | bboxes [BS,NA,4] | scores [BS,NA,NC] | fg [BS,NA]
#define OUT_LABELS 0
#define OUT_BBOX   (BS * NA)
#define OUT_SCORES (BS * NA * 5)
#define OUT_FG     (BS * NA * 5 + BS * NA * NC)

// ws (u32 units): cm[BS*NA] (packed cnt<<20 | sum_m) | posalign[1600] | posover[1600]
//                 | alignbuf f32[BS*NA] | idxbuf i32[BS*NA]
#define CM_OFF   0
#define PA_OFF   (BS * NA)
#define PO_OFF   (BS * NA + BS * NMB)
#define AB_OFF   (BS * NA + 2 * BS * NMB)
#define IDX_OFF  (AB_OFF + BS * NA)

#define ZERO_U32 (BS * NA + 2 * BS * NMB)     // 137600, divisible by 4
#define INIT_VEC (ZERO_U32 / 4)               // 34400 uint4 stores

__device__ __forceinline__ float iou_xyxy(float4 g, float4 p) {
    float lx = fmaxf(g.x, p.x), ly = fmaxf(g.y, p.y);
    float rx = fminf(g.z, p.z), ry = fminf(g.w, p.w);
    float w = fmaxf(rx - lx, 0.f), h = fmaxf(ry - ly, 0.f);
    float inter = w * h;
    float ag = (g.z - g.x) * (g.w - g.y);
    float ap = (p.z - p.x) * (p.w - p.y);
    return inter / (ag + ap - inter + EPS);
}

// fast unsigned divide for small c (<4096), w (<128): rcp + correction
__device__ __forceinline__ void fdivmod(int c, int w, float rw, int& q, int& r) {
    q = (int)((float)c * rw);
    r = c - q * w;
    if (r < 0) { q--; r += w; }
    else if (r >= w) { q++; r -= w; }
}

// Zero cm + posalign + posover (550 KB). Replaces hipMemsetAsync (slow fill path).
__global__ __launch_bounds__(256) void k_init(uint4* __restrict__ ws) {
    int t = blockIdx.x * 256 + threadIdx.x;
    if (t < INIT_VEC) ws[t] = make_uint4(0u, 0u, 0u, 0u);
}

// One WAVE per (b,m). Candidates = in-box anchors (3 padded rectangular grid
// ranges, exact ins filter) + anchors {0..12} (the only possible zero-value
// tie-break picks), deduped. Top-13 via 13 rounds of wave argmax on packed
// (value<<32 | ~idx) keys -> exact jax.lax.top_k order (value desc, idx asc).
// Winners scatter ONE packed atomic: cm[b,a] += (1<<20)|m. Then
// cnt = cm>>20 and, when cnt==1, (cm & 0xFFFFF) is that single m.
// (sum of m over winners <= 4950 < 2^20 -> no overflow.)
__global__ __launch_bounds__(64) void k_topk(
        const float* __restrict__ scores, const float* __restrict__ pboxes,
        const float* __restrict__ gboxes, const float* __restrict__ maskgt,
        const int* __restrict__ glabels,
        unsigned int* __restrict__ cm) {
    int bid = blockIdx.x;
    int bm = (bid & 7) * 200 + (bid >> 3);     // 8 XCDs x 200: 2 batches per XCD
    if (maskgt[bm] <= 0.f) return;             // masked GT: no candidates at all
    int b = bm / NMB, mm = bm - b * NMB;
    float4 g = ((const float4*)gboxes)[bm];
    int lbl = glabels[bm];
    int lane = threadIdx.x;
    const float* srow = scores + (size_t)b * NA * NC + lbl;
    const float4* pb = (const float4*)pboxes + (size_t)b * NA;

    // padded index ranges per level; ins test below is the exact filter.
    int x0, y0, w0, h0, x1r, y1r, w1, h1, x2r, y2r, w2, h2;
    {
        float s = 8.f; int n = 80;
        x0 = (int)floorf((g.x + EPS) / s - 0.5f); if (x0 < 0) x0 = 0;
        int xh = (int)ceilf((g.z - EPS) / s - 0.5f); if (xh > n - 1) xh = n - 1;
        y0 = (int)floorf((g.y + EPS) / s - 0.5f); if (y0 < 0) y0 = 0;
        int yh = (int)ceilf((g.w - EPS) / s - 0.5f); if (yh > n - 1) yh = n - 1;
        w0 = xh - x0 + 1; if (w0 < 0) w0 = 0;
        h0 = yh - y0 + 1; if (h0 < 0) h0 = 0;
    }
    {
        float s = 16.f; int n = 40;
        x1r = (int)floorf((g.x + EPS) / s - 0.5f); if (x1r < 0) x1r = 0;
        int xh = (int)ceilf((g.z - EPS) / s - 0.5f); if (xh > n - 1) xh = n - 1;
        y1r = (int)floorf((g.y + EPS) / s - 0.5f); if (y1r < 0) y1r = 0;
        int yh = (int)ceilf((g.w - EPS) / s - 0.5f); if (yh > n - 1) yh = n - 1;
        w1 = xh - x1r + 1; if (w1 < 0) w1 = 0;
        h1 = yh - y1r + 1; if (h1 < 0) h1 = 0;
    }
    {
        float s = 32.f; int n = 20;
        x2r = (int)floorf((g.x + EPS) / s - 0.5f); if (x2r < 0) x2r = 0;
        int xh = (int)ceilf((g.z - EPS) / s - 0.5f); if (xh > n - 1) xh = n - 1;
        y2r = (int)floorf((g.y + EPS) / s - 0.5f); if (y2r < 0) y2r = 0;
        int yh = (int)ceilf((g.w - EPS) / s - 0.5f); if (yh > n - 1) yh = n - 1;
        w2 = xh - x2r + 1; if (w2 < 0) w2 = 0;
        h2 = yh - y2r + 1; if (h2 < 0) h2 = 0;
    }
    int n0 = w0 * h0, n01 = n0 + w1 * h1, n012 = n01 + w2 * h2;
    int N = n012 + TOPK;                       // <= ~570 + 13 <= 640 = 64*10
    float rw0 = __builtin_amdgcn_rcpf((float)w0);
    float rw1 = __builtin_amdgcn_rcpf((float)w1);
    float rw2 = __builtin_amdgcn_rcpf((float)w2);

    unsigned long long key[10];
    unsigned int insmask = 0;
    #pragma unroll
    for (int j = 0; j < 10; ++j) {
        key[j] = 0ull;
        int c = lane + j * 64;
        if (c < N) {
            int a; float ax, ay; bool dup = false;
            if (c < n0) {
                int iy, ix; fdivmod(c, w0, rw0, iy, ix);
                iy += y0; ix += x0;
                a = iy * 80 + ix; ax = (ix + 0.5f) * 8.f; ay = (iy + 0.5f) * 8.f;
            } else if (c < n01) {
                int iy, ix; fdivmod(c - n0, w1, rw1, iy, ix);
                iy += y1r; ix += x1r;
                a = 6400 + iy * 40 + ix; ax = (ix + 0.5f) * 16.f; ay = (iy + 0.5f) * 16.f;
            } else if (c < n012) {
                int iy, ix; fdivmod(c - n01, w2, rw2, iy, ix);
                iy += y2r; ix += x2r;
                a = 8000 + iy * 20 + ix; ax = (ix + 0.5f) * 32.f; ay = (iy + 0.5f) * 32.f;
            } else {
                a = c - n012;                  // supplement: L0 row 0, ix=a
                ax = (a + 0.5f) * 8.f; ay = 4.0f;
                dup = (h0 > 0) && (y0 == 0) && (w0 > 0) && (x0 <= a) && (a <= x0 + w0 - 1);
            }
            if (!dup) {
                float4 p = pb[a];
                float sc = srow[(size_t)a * NC];
                float ov = iou_xyxy(g, p);
                bool ins = fminf(fminf(ax - g.x, ay - g.y),
                                 fminf(g.z - ax, g.w - ay)) > EPS;
                float o2 = ov * ov;
                float val = ins ? sc * o2 * o2 * o2 : 0.f;
                key[j] = ((unsigned long long)__float_as_uint(val) << 32)
                       | (unsigned)(0xFFFFFFFFu - (unsigned)a);
                if (ins) insmask |= (1u << j);
            }
        }
    }

    for (int r = 0; r < TOPK; ++r) {
        unsigned long long best = 0ull;
        #pragma unroll
        for (int j = 0; j < 10; ++j) if (key[j] > best) best = key[j];
        #pragma unroll
        for (int off = 32; off >= 1; off >>= 1) {
            unsigned long long o = __shfl_xor(best, off, 64);
            if (o > best) best = o;
        }
        #pragma unroll
        for (int j = 0; j < 10; ++j) {
            if (key[j] == best) {              // unique owner (>=13 nonzero keys)
                key[j] = 0ull;
                if ((insmask >> j) & 1u) {     // mark only if is_in_gts
                    int a = (int)(0xFFFFFFFFu - (unsigned)best);
                    atomicAdd(&cm[b * NA + a], (1u << 20) | (unsigned)mm);
                }
            }
        }
    }
}

// One thread per (b,a); 33 blocks per batch (b uniform per block).
// cnt/min-m in ONE cm load; 100-GT IoU argmax only for the rare cnt>1 anchors.
// Collision resolution, labels/bboxes/fg outputs, per-GT maxima atomics.
__global__ __launch_bounds__(256) void k_resolve(
        const float* __restrict__ scores, const float* __restrict__ pboxes,
        const float* __restrict__ gboxes, const int* __restrict__ glabels,
        const unsigned int* __restrict__ cm,
        unsigned int* __restrict__ posalign, unsigned int* __restrict__ posover,
        float* __restrict__ alignbuf, int* __restrict__ idxbuf,
        float* __restrict__ out) {
    int blk = blockIdx.x;
    int b = blk / 33;
    int a = (blk - b * 33) * 256 + threadIdx.x;
    if (a >= NA) return;
    int t = b * NA + a;

    unsigned int c = cm[t];
    int cnt = (int)(c >> 20);
    float4 p = ((const float4*)pboxes)[t];
    int idx = 0, fg = 0;
    if (cnt == 1) { idx = (int)(c & 0xFFFFFu); fg = 1; }
    else if (cnt > 1) {
        // multi-GT anchor -> argmax_m IoU over ALL m (first occurrence on ties)
        float best = -1.f; int bmx = 0;
        for (int m = 0; m < NMB; ++m) {
            float4 gg = ((const float4*)gboxes)[b * NMB + m];   // L2-resident
            float ov = iou_xyxy(gg, p);
            if (ov > best) { best = ov; bmx = m; }
        }
        idx = bmx; fg = 1;
    }

    int lbl = glabels[b * NMB + idx];
    if (lbl < 0) lbl = 0;
    float4 gb = ((const float4*)gboxes)[b * NMB + idx];
    float al = 0.f;
    if (fg) {
        float ov = iou_xyxy(gb, p);
        float sc = scores[(size_t)t * NC + lbl];
        float o2 = ov * ov;
        al = sc * o2 * o2 * o2;                // UNMASKED align (matches ref)
        atomicMax(&posalign[b * NMB + idx], __float_as_uint(al));
        atomicMax(&posover[b * NMB + idx], __float_as_uint(ov));
    }
    alignbuf[t] = al;
    idxbuf[t] = fg ? idx : -1;
    out[OUT_LABELS + t] = (float)lbl;          // gather NOT masked by fg (ref)
    ((float4*)(out + OUT_BBOX))[t] = gb;
    out[OUT_FG + t] = fg ? 1.f : 0.f;
}

// One thread per 16-byte chunk of the score output (20 chunks per anchor).
// Fully coalesced plain float4 stores through L2 (write-combining).
// norm = align*pos_over/(pos_align+eps) at the single assigned GT.
__global__ __launch_bounds__(256) void k_score(
        const float* __restrict__ alignbuf, const int* __restrict__ idxbuf,
        const int* __restrict__ glabels,
        const unsigned int* __restrict__ posalign,
        const unsigned int* __restrict__ posover,
        float* __restrict__ out) {
    int i = blockIdx.x * 256 + threadIdx.x;
    if (i >= BS * NA * (NC / 4)) return;
    int t = i / (NC / 4), q = i - t * (NC / 4);   // anchor, chunk
    int b = t / NA;
    int idx = idxbuf[t];
    float norm = 0.f; int lbl = -1;
    if (idx >= 0) {
        float pa = __uint_as_float(posalign[b * NMB + idx]);
        float po = __uint_as_float(posover[b * NMB + idx]);
        norm = alignbuf[t] * po / (pa + EPS);
        lbl = glabels[b * NMB + idx];
        if (lbl < 0) lbl = 0;
    }
    int c0 = q * 4;
    f32x4 w;
    w.x = (c0     == lbl) ? norm : 0.f;
    w.y = (c0 + 1 == lbl) ? norm : 0.f;
    w.z = (c0 + 2 == lbl) ? norm : 0.f;
    w.w = (c0 + 3 == lbl) ? norm : 0.f;
    ((f32x4*)(out + OUT_SCORES))[i] = w;
}

extern "C" void kernel_launch(void* const* d_in, const int* in_sizes, int n_in,
                              void* d_out, int out_size, void* d_ws, size_t ws_size,
                              hipStream_t stream) {
    const float* scores  = (const float*)d_in[0];   // [BS,NA,NC]
    const float* pboxes  = (const float*)d_in[1];   // [BS,NA,4]
    const float* gboxes  = (const float*)d_in[3];   // [BS,NMB,4]
    const float* maskgt  = (const float*)d_in[4];   // [BS,NMB,1]
    const int*   glabels = (const int*)d_in[5];     // [BS,NMB,1]
    float* out = (float*)d_out;

    unsigned int* ws = (unsigned int*)d_ws;
    unsigned int* cmbuf    = ws + CM_OFF;
    unsigned int* posalign = ws + PA_OFF;
    unsigned int* posover  = ws + PO_OFF;
    float* alignbuf        = (float*)(ws + AB_OFF);
    int*   idxbuf          = (int*)(ws + IDX_OFF);

    k_init<<<(INIT_VEC + 255) / 256, 256, 0, stream>>>((uint4*)d_ws);
    k_topk<<<BS * NMB, 64, 0, stream>>>(scores, pboxes, gboxes, maskgt,
                                        glabels, cmbuf);
    k_resolve<<<BS * 33, 256, 0, stream>>>(
        scores, pboxes, gboxes, glabels, cmbuf,
        posalign, posover, alignbuf, idxbuf, out);
    int nchunk = BS * NA * (NC / 4);
    k_score<<<(nchunk + 255) / 256, 256, 0, stream>>>(
        alignbuf, idxbuf, glabels, posalign, posover, out);
}

// Round 9
// 59.697 us; speedup vs baseline: 2.7710x; 1.0040x over previous
//
#include <hip/hip_runtime.h>
#include <hip/hip_bf16.h>

#define BS   16
#define NA   8400
#define NMB  100
#define NC   80
#define TOPK 13
#define EPS  1e-9f

typedef float f32x4 __attribute__((ext_vector_type(4)));

// output layout (floats): labels [BS,NA] | bboxes [BS,NA,4] | scores [BS,NA,NC] | fg [BS,NA]
#define OUT_LABELS 0
#define OUT_BBOX   (BS * NA)
#define OUT_SCORES (BS * NA * 5)
#define OUT_FG     (BS * NA * 5 + BS * NA * NC)

// ws (u32 units): cm[BS*NA] (packed cnt<<20 | sum_m) | posalign[1600] | posover[1600]
//                 | alignbuf f32[BS*NA] | idxbuf i32[BS*NA]
#define CM_OFF   0
#define PA_OFF   (BS * NA)
#define PO_OFF   (BS * NA + BS * NMB)
#define AB_OFF   (BS * NA + 2 * BS * NMB)
#define IDX_OFF  (AB_OFF + BS * NA)

#define ZERO_U32 (BS * NA + 2 * BS * NMB)     // 137600, divisible by 4
#define INIT_VEC (ZERO_U32 / 4)               // 34400 uint4 stores

__device__ __forceinline__ float iou_xyxy(float4 g, float4 p) {
    float lx = fmaxf(g.x, p.x), ly = fmaxf(g.y, p.y);
    float rx = fminf(g.z, p.z), ry = fminf(g.w, p.w);
    float w = fmaxf(rx - lx, 0.f), h = fmaxf(ry - ly, 0.f);
    float inter = w * h;
    float ag = (g.z - g.x) * (g.w - g.y);
    float ap = (p.z - p.x) * (p.w - p.y);
    return inter / (ag + ap - inter + EPS);
}

// fast unsigned divide for small c (<4096), w (<128): rcp + correction
__device__ __forceinline__ void fdivmod(int c, int w, float rw, int& q, int& r) {
    q = (int)((float)c * rw);
    r = c - q * w;
    if (r < 0) { q--; r += w; }
    else if (r >= w) { q++; r -= w; }
}

// Zero cm + posalign + posover (550 KB). Replaces hipMemsetAsync (slow fill path).
__global__ __launch_bounds__(256) void k_init(uint4* __restrict__ ws) {
    int t = blockIdx.x * 256 + threadIdx.x;
    if (t < INIT_VEC) ws[t] = make_uint4(0u, 0u, 0u, 0u);
}

// One WAVE per (b,m), 4 GTs per 256-thread block. Candidates = in-box anchors
// (3 padded rectangular grid ranges, exact ins filter) + anchors {0..12} (the
// only possible zero-value tie-break picks), deduped. Top-13 via 13 rounds of
// wave argmax on packed (value<<32 | ~idx) keys -> exact jax.lax.top_k order
// (value desc, idx asc). Winners scatter ONE packed atomic:
// cm[b,a] += (1<<20)|m  =>  cnt = cm>>20; cnt==1 -> low bits = that m.
// (sum of m over winners <= 4950 < 2^20 -> no overflow.)
__global__ __launch_bounds__(256) void k_topk(
        const float* __restrict__ scores, const float* __restrict__ pboxes,
        const float* __restrict__ gboxes, const float* __restrict__ maskgt,
        const int* __restrict__ glabels,
        unsigned int* __restrict__ cm) {
    int bid = blockIdx.x;
    int gid = (bid & 7) * 50 + (bid >> 3);     // 8 XCDs x 50 block-groups
    int bm = gid * 4 + (threadIdx.x >> 6);     // wave -> GT
    if (maskgt[bm] <= 0.f) return;             // masked GT: no candidates at all
    int b = bm / NMB, mm = bm - b * NMB;
    float4 g = ((const float4*)gboxes)[bm];
    int lbl = glabels[bm];
    int lane = threadIdx.x & 63;
    const float* srow = scores + (size_t)b * NA * NC + lbl;
    const float4* pb = (const float4*)pboxes + (size_t)b * NA;

    // padded index ranges per level; ins test below is the exact filter.
    int x0, y0, w0, h0, x1r, y1r, w1, h1, x2r, y2r, w2, h2;
    {
        float s = 8.f; int n = 80;
        x0 = (int)floorf((g.x + EPS) / s - 0.5f); if (x0 < 0) x0 = 0;
        int xh = (int)ceilf((g.z - EPS) / s - 0.5f); if (xh > n - 1) xh = n - 1;
        y0 = (int)floorf((g.y + EPS) / s - 0.5f); if (y0 < 0) y0 = 0;
        int yh = (int)ceilf((g.w - EPS) / s - 0.5f); if (yh > n - 1) yh = n - 1;
        w0 = xh - x0 + 1; if (w0 < 0) w0 = 0;
        h0 = yh - y0 + 1; if (h0 < 0) h0 = 0;
    }
    {
        float s = 16.f; int n = 40;
        x1r = (int)floorf((g.x + EPS) / s - 0.5f); if (x1r < 0) x1r = 0;
        int xh = (int)ceilf((g.z - EPS) / s - 0.5f); if (xh > n - 1) xh = n - 1;
        y1r = (int)floorf((g.y + EPS) / s - 0.5f); if (y1r < 0) y1r = 0;
        int yh = (int)ceilf((g.w - EPS) / s - 0.5f); if (yh > n - 1) yh = n - 1;
        w1 = xh - x1r + 1; if (w1 < 0) w1 = 0;
        h1 = yh - y1r + 1; if (h1 < 0) h1 = 0;
    }
    {
        float s = 32.f; int n = 20;
        x2r = (int)floorf((g.x + EPS) / s - 0.5f); if (x2r < 0) x2r = 0;
        int xh = (int)ceilf((g.z - EPS) / s - 0.5f); if (xh > n - 1) xh = n - 1;
        y2r = (int)floorf((g.y + EPS) / s - 0.5f); if (y2r < 0) y2r = 0;
        int yh = (int)ceilf((g.w - EPS) / s - 0.5f); if (yh > n - 1) yh = n - 1;
        w2 = xh - x2r + 1; if (w2 < 0) w2 = 0;
        h2 = yh - y2r + 1; if (h2 < 0) h2 = 0;
    }
    int n0 = w0 * h0, n01 = n0 + w1 * h1, n012 = n01 + w2 * h2;
    int N = n012 + TOPK;                       // <= ~570 + 13 <= 640 = 64*10
    float rw0 = __builtin_amdgcn_rcpf((float)w0);
    float rw1 = __builtin_amdgcn_rcpf((float)w1);
    float rw2 = __builtin_amdgcn_rcpf((float)w2);

    unsigned long long key[10];
    unsigned int insmask = 0;
    #pragma unroll
    for (int j = 0; j < 10; ++j) {
        key[j] = 0ull;
        int c = lane + j * 64;
        if (c < N) {
            int a; float ax, ay; bool dup = false;
            if (c < n0) {
                int iy, ix; fdivmod(c, w0, rw0, iy, ix);
                iy += y0; ix += x0;
                a = iy * 80 + ix; ax = (ix + 0.5f) * 8.f; ay = (iy + 0.5f) * 8.f;
            } else if (c < n01) {
                int iy, ix; fdivmod(c - n0, w1, rw1, iy, ix);
                iy += y1r; ix += x1r;
                a = 6400 + iy * 40 + ix; ax = (ix + 0.5f) * 16.f; ay = (iy + 0.5f) * 16.f;
            } else if (c < n012) {
                int iy, ix; fdivmod(c - n01, w2, rw2, iy, ix);
                iy += y2r; ix += x2r;
                a = 8000 + iy * 20 + ix; ax = (ix + 0.5f) * 32.f; ay = (iy + 0.5f) * 32.f;
            } else {
                a = c - n012;                  // supplement: L0 row 0, ix=a
                ax = (a + 0.5f) * 8.f; ay = 4.0f;
                dup = (h0 > 0) && (y0 == 0) && (w0 > 0) && (x0 <= a) && (a <= x0 + w0 - 1);
            }
            if (!dup) {
                float4 p = pb[a];
                float sc = srow[(size_t)a * NC];
                float ov = iou_xyxy(g, p);
                bool ins = fminf(fminf(ax - g.x, ay - g.y),
                                 fminf(g.z - ax, g.w - ay)) > EPS;
                float o2 = ov * ov;
                float val = ins ? sc * o2 * o2 * o2 : 0.f;
                key[j] = ((unsigned long long)__float_as_uint(val) << 32)
                       | (unsigned)(0xFFFFFFFFu - (unsigned)a);
                if (ins) insmask |= (1u << j);
            }
        }
    }

    for (int r = 0; r < TOPK; ++r) {
        unsigned long long best = 0ull;
        #pragma unroll
        for (int j = 0; j < 10; ++j) if (key[j] > best) best = key[j];
        #pragma unroll
        for (int off = 32; off >= 1; off >>= 1) {
            unsigned long long o = __shfl_xor(best, off, 64);
            if (o > best) best = o;
        }
        #pragma unroll
        for (int j = 0; j < 10; ++j) {
            if (key[j] == best) {              // unique owner (>=13 nonzero keys)
                key[j] = 0ull;
                if ((insmask >> j) & 1u) {     // mark only if is_in_gts
                    int a = (int)(0xFFFFFFFFu - (unsigned)best);
                    atomicAdd(&cm[b * NA + a], (1u << 20) | (unsigned)mm);
                }
            }
        }
    }
}

// One thread per (b,a); 33 blocks per batch (b uniform per block).
// gboxes+labels staged in LDS (kills wave-uniform global-load stalls in the
// cnt>1 path). cnt/min-m come from ONE cm load. Collision resolution,
// labels/bboxes/fg outputs, per-GT maxima atomics.
__global__ __launch_bounds__(256) void k_resolve(
        const float* __restrict__ scores, const float* __restrict__ pboxes,
        const float* __restrict__ gboxes, const int* __restrict__ glabels,
        const unsigned int* __restrict__ cm,
        unsigned int* __restrict__ posalign, unsigned int* __restrict__ posover,
        float* __restrict__ alignbuf, int* __restrict__ idxbuf,
        float* __restrict__ out) {
    __shared__ float4 s_g[NMB];
    __shared__ int s_lbl[NMB];
    int blk = blockIdx.x;
    int b = blk / 33;
    int a = (blk - b * 33) * 256 + threadIdx.x;
    if (threadIdx.x < NMB) {
        s_g[threadIdx.x] = ((const float4*)gboxes)[b * NMB + threadIdx.x];
        s_lbl[threadIdx.x] = glabels[b * NMB + threadIdx.x];
    }
    __syncthreads();
    if (a >= NA) return;
    int t = b * NA + a;

    unsigned int c = cm[t];
    int cnt = (int)(c >> 20);
    float4 p = ((const float4*)pboxes)[t];
    int idx = 0, fg = 0;
    if (cnt == 1) { idx = (int)(c & 0xFFFFFu); fg = 1; }
    else if (cnt > 1) {
        // multi-GT anchor -> argmax_m IoU over ALL m (first occurrence on ties)
        float best = -1.f; int bmx = 0;
        #pragma unroll 4
        for (int m = 0; m < NMB; ++m) {
            float ov = iou_xyxy(s_g[m], p);
            if (ov > best) { best = ov; bmx = m; }
        }
        idx = bmx; fg = 1;
    }

    int lbl = s_lbl[idx];
    if (lbl < 0) lbl = 0;
    float4 gb = s_g[idx];
    float al = 0.f;
    if (fg) {
        float ov = iou_xyxy(gb, p);
        float sc = scores[(size_t)t * NC + lbl];
        float o2 = ov * ov;
        al = sc * o2 * o2 * o2;                // UNMASKED align (matches ref)
        atomicMax(&posalign[b * NMB + idx], __float_as_uint(al));
        atomicMax(&posover[b * NMB + idx], __float_as_uint(ov));
    }
    alignbuf[t] = al;
    idxbuf[t] = fg ? idx : -1;
    out[OUT_LABELS + t] = (float)lbl;          // gather NOT masked by fg (ref)
    ((float4*)(out + OUT_BBOX))[t] = gb;
    out[OUT_FG + t] = fg ? 1.f : 0.f;
}

// One thread per 16-byte chunk of the score output (20 chunks per anchor).
// Fully coalesced plain float4 stores through L2 (write-combining).
// norm = align*pos_over/(pos_align+eps) at the single assigned GT.
__global__ __launch_bounds__(256) void k_score(
        const float* __restrict__ alignbuf, const int* __restrict__ idxbuf,
        const int* __restrict__ glabels,
        const unsigned int* __restrict__ posalign,
        const unsigned int* __restrict__ posover,
        float* __restrict__ out) {
    int i = blockIdx.x * 256 + threadIdx.x;
    if (i >= BS * NA * (NC / 4)) return;
    int t = i / (NC / 4), q = i - t * (NC / 4);   // anchor, chunk
    int b = t / NA;
    int idx = idxbuf[t];
    float norm = 0.f; int lbl = -1;
    if (idx >= 0) {
        float pa = __uint_as_float(posalign[b * NMB + idx]);
        float po = __uint_as_float(posover[b * NMB + idx]);
        norm = alignbuf[t] * po / (pa + EPS);
        lbl = glabels[b * NMB + idx];
        if (lbl < 0) lbl = 0;
    }
    int c0 = q * 4;
    f32x4 w;
    w.x = (c0     == lbl) ? norm : 0.f;
    w.y = (c0 + 1 == lbl) ? norm : 0.f;
    w.z = (c0 + 2 == lbl) ? norm : 0.f;
    w.w = (c0 + 3 == lbl) ? norm : 0.f;
    ((f32x4*)(out + OUT_SCORES))[i] = w;
}

extern "C" void kernel_launch(void* const* d_in, const int* in_sizes, int n_in,
                              void* d_out, int out_size, void* d_ws, size_t ws_size,
                              hipStream_t stream) {
    const float* scores  = (const float*)d_in[0];   // [BS,NA,NC]
    const float* pboxes  = (const float*)d_in[1];   // [BS,NA,4]
    const float* gboxes  = (const float*)d_in[3];   // [BS,NMB,4]
    const float* maskgt  = (const float*)d_in[4];   // [BS,NMB,1]
    const int*   glabels = (const int*)d_in[5];     // [BS,NMB,1]
    float* out = (float*)d_out;

    unsigned int* ws = (unsigned int*)d_ws;
    unsigned int* cmbuf    = ws + CM_OFF;
    unsigned int* posalign = ws + PA_OFF;
    unsigned int* posover  = ws + PO_OFF;
    float* alignbuf        = (float*)(ws + AB_OFF);
    int*   idxbuf          = (int*)(ws + IDX_OFF);

    k_init<<<(INIT_VEC + 255) / 256, 256, 0, stream>>>((uint4*)d_ws);
    k_topk<<<BS * NMB / 4, 256, 0, stream>>>(scores, pboxes, gboxes, maskgt,
                                             glabels, cmbuf);
    k_resolve<<<BS * 33, 256, 0, stream>>>(
        scores, pboxes, gboxes, glabels, cmbuf,
        posalign, posover, alignbuf, idxbuf, out);
    int nchunk = BS * NA * (NC / 4);
    k_score<<<(nchunk + 255) / 256, 256, 0, stream>>>(
        alignbuf, idxbuf, glabels, posalign, posover, out);
}